// Round 5
// baseline (137.974 us; speedup 1.0000x reference)
//
#include <hip/hip_runtime.h>
#include <math.h>

// Problem constants (from reference setup_inputs)
constexpr int   BSZ   = 16;
constexpr int   NDIM  = 128;
constexpr int   KP1   = 65537;      // K+1
constexpr long  NDATA = 500000;
constexpr float T_INV = 1.0f / 0.07f;
constexpr float MOM   = 0.5f;
constexpr float EPS   = 1e-12f;

typedef float v4f __attribute__((ext_vector_type(4)));

// ---------------- sweep path: sequential sweep + dots table ----------------
constexpr int  TROWS    = 64;                    // rows per tile (= lanes)
constexpr int  NTILES   = (int)((NDATA + TROWS - 1) / TROWS);   // 7813
constexpr int  LDP      = NDIM + 1;              // 129 pad: column reads 2-way-free
constexpr int  K1_BLOCKS = 1024;                 // 4 single-wave blocks/CU (LDS-bound)
constexpr int  NLOG     = BSZ * KP1;             // 1,048,592
constexpr int  K2_GBLK  = (NLOG + 255) / 256;    // 4097
constexpr long DOTS_ELEMS = (long)BSZ * NDATA;   // 8,000,000 floats (32 MB)
constexpr size_t WS_NEED = (size_t)(DOTS_ELEMS + BSZ * NDIM) * 4;

// k0: transpose x[16][128] -> xT[128][16] (workspace)
__global__ __launch_bounds__(256) void xpose_kernel(
        const float* __restrict__ x, float* __restrict__ xT) {
    const int t = blockIdx.x * 256 + threadIdx.x;
    if (t < BSZ * NDIM) {
        const int b = t >> 7, d = t & 127;
        xT[d * BSZ + b] = x[t];
    }
}

// k1: software-pipelined sequential sweep over memory.
// Per 64-row tile (one wave): regs hold tile t (NT-loaded last iteration);
// drain regs -> LDS (pad-129) + NT copy-store, then ISSUE tile t+stride's
// 32 NT loads (no consumer until next drain -> they fly during compute),
// then lane l = row l computes 16 fp32 dots from LDS against xT (wave-
// uniform s_load rows). HBM latency hides under the ~4.3k-cycle dot loop;
// single wave per block -> no barriers (DS ops in-order per wave).
__global__ __launch_bounds__(64, 1) void dots_copy_kernel(
        const float* __restrict__ memory,
        const float* __restrict__ xT,
        float*       __restrict__ dots,
        float*       __restrict__ out) {
    __shared__ float tile[TROWS * LDP];
    const int l = threadIdx.x;
    v4f buf[32];

    int t = blockIdx.x;                      // K1_BLOCKS <= NTILES always
    { // prologue: prefetch first tile
        const v4f* __restrict__ srcp = (const v4f*)(memory + (long)t * (TROWS * NDIM));
        const long rem = NDATA - (long)t * TROWS;
        const int nf4 = (int)((rem < TROWS) ? rem : TROWS) * (NDIM / 4);
        #pragma unroll
        for (int c = 0; c < 32; ++c) {
            int fi = c * 64 + l;
            fi = (fi < nf4) ? fi : (nf4 - 1);
            buf[c] = __builtin_nontemporal_load(srcp + fi);
        }
    }

    while (t < NTILES) {
        const long j0   = (long)t * TROWS;
        const long rem  = NDATA - j0;
        const int  rows = (int)((rem < TROWS) ? rem : TROWS);
        const int  nf4  = rows * (NDIM / 4);
        v4f* __restrict__ dst = (v4f*)(out + j0 * NDIM);

        // A: drain regs -> LDS tile + NT copy-store (reads buf at issue)
        #pragma unroll
        for (int c = 0; c < 32; ++c) {
            const int fi = c * 64 + l;
            const int r = fi >> 5, col = (fi & 31) * 4;
            float* p = &tile[r * LDP + col];
            p[0] = buf[c].x; p[1] = buf[c].y; p[2] = buf[c].z; p[3] = buf[c].w;
            if (fi < nf4)
                __builtin_nontemporal_store(buf[c], dst + fi);
        }

        // B: issue next tile's loads now; they fly during the compute below
        const int tn = t + K1_BLOCKS;
        if (tn < NTILES) {
            const v4f* __restrict__ srcp =
                (const v4f*)(memory + (long)tn * (TROWS * NDIM));
            const long remn = NDATA - (long)tn * TROWS;
            const int nf4n = (int)((remn < TROWS) ? remn : TROWS) * (NDIM / 4);
            #pragma unroll
            for (int c = 0; c < 32; ++c) {
                int fi = c * 64 + l;
                fi = (fi < nf4n) ? fi : (nf4n - 1);
                buf[c] = __builtin_nontemporal_load(srcp + fi);
            }
        }

        // C: compute 16 dots for row l from the LDS tile
        float acc[BSZ];
        #pragma unroll
        for (int b = 0; b < BSZ; ++b) acc[b] = 0.0f;

        const float* __restrict__ mrow = &tile[l * LDP];
        #pragma unroll 4
        for (int dd = 0; dd < NDIM; ++dd) {
            const float m = mrow[dd];               // 2-way bank alias: free
            const float* __restrict__ xv = &xT[dd * BSZ];   // wave-uniform
            #pragma unroll
            for (int b = 0; b < BSZ; ++b)
                acc[b] = fmaf(m, xv[b], acc[b]);
        }

        if (l < rows) {
            #pragma unroll
            for (int b = 0; b < BSZ; ++b)
                dots[(long)b * NDATA + j0 + l] = acc[b];   // 256B coalesced
        }
        t = tn;
    }
}

// k2: logits gather from the L3-resident dots table + fused EMA update.
__global__ __launch_bounds__(256) void gather_kernel(
        const float* __restrict__ x,
        const int*   __restrict__ y,
        const int*   __restrict__ idx,
        const float* __restrict__ memory,
        const float* __restrict__ dots,
        float*       __restrict__ logits,
        float*       __restrict__ labels,
        float*       __restrict__ out_mem) {
    const int bid = blockIdx.x;
    if (bid < K2_GBLK) {
        const int g = bid * 256 + threadIdx.x;
        if (g < NLOG) {
            const int b = g / KP1;
            const int k = g - b * KP1;
            const int j = (k == 0) ? y[b] : idx[g];
            logits[g] = dots[(long)b * NDATA + j] * T_INV;
        }
        return;
    }
    // ---- update role: 16 blocks, one wave each ----
    const int b = bid - K2_GBLK;
    const int lane = threadIdx.x;
    if (lane >= 64) return;
    const int yb = y[b];
    const float2 m  = ((const float2*)(memory + (size_t)yb * NDIM))[lane];
    const float2 xv = ((const float2*)(x + (size_t)b * NDIM))[lane];
    float2 v;
    v.x = m.x * MOM + xv.x * (1.0f - MOM);
    v.y = m.y * MOM + xv.y * (1.0f - MOM);
    float s = v.x * v.x + v.y * v.y;
    #pragma unroll
    for (int off = 32; off > 0; off >>= 1)
        s += __shfl_xor(s, off, 64);
    const float n = fmaxf(sqrtf(s), EPS);
    float2 o; o.x = v.x / n; o.y = v.y / n;
    ((float2*)(out_mem + (size_t)yb * NDIM))[lane] = o;
    if (lane == 0) labels[b] = 0.0f;
}

// ---------------- fallback path (round-3 fused kernel) ----------------
constexpr int U    = 8;
constexpr int NBX  = 128;
constexpr int NCPY = 2048;
constexpr int N4   = (int)(NDATA * NDIM / 4);

__device__ __forceinline__ float merge_pair(float a, float b, int bit, int lane) {
    const float keep = (lane & bit) ? b : a;
    const float send = (lane & bit) ? a : b;
    return keep + __shfl_xor(send, bit, 64);
}

__global__ __launch_bounds__(256, 8) void fused_kernel(
        const float*  __restrict__ x,
        const int*    __restrict__ y,
        const int*    __restrict__ idx,
        const float*  __restrict__ memory,
        float*        __restrict__ logits,
        v4f*          __restrict__ out4) {
    const int bid = blockIdx.x;
    const int sub = bid >> 1;
    if ((bid & 1) == 0) {
        const v4f* __restrict__ src = (const v4f*)memory;
        const int stride = NCPY * 256;
        for (int i = sub * 256 + threadIdx.x; i < N4; i += stride) {
            const v4f v = src[i];
            __builtin_nontemporal_store(v, out4 + i);
        }
        return;
    }
    const int bx   = sub & (NBX - 1);
    const int b    = sub >> 7;
    const int lane = threadIdx.x & 63;
    const int wid  = threadIdx.x >> 6;
    const int nwaves = NBX * 4;
    const int gwave  = bx * 4 + wid;
    const float2 xv = ((const float2*)(x + (size_t)b * NDIM))[lane];
    const int yb = y[b];
    const int* __restrict__ idxb = idx + (size_t)b * KP1;
    const float2* __restrict__ mem2 = (const float2*)memory;
    float* __restrict__ outb = logits + (size_t)b * KP1;
    const int chunk = (KP1 + nwaves - 1) / nwaves;
    const int k0 = gwave * chunk;
    const int k1 = min(k0 + chunk, KP1);
    for (int k = k0; k < k1; k += U) {
        int j[U];
        #pragma unroll
        for (int u = 0; u < U; ++u) {
            int kc = k + u;
            kc = (kc < KP1) ? kc : (KP1 - 1);
            j[u] = (kc == 0) ? yb : idxb[kc];
        }
        float2 m[U];
        #pragma unroll
        for (int u = 0; u < U; ++u)
            m[u] = mem2[(size_t)j[u] * (NDIM / 2) + lane];
        float s[U];
        #pragma unroll
        for (int u = 0; u < U; ++u)
            s[u] = m[u].x * xv.x + m[u].y * xv.y;
        float m0 = merge_pair(s[0], s[4], 32, lane);
        float m1 = merge_pair(s[1], s[5], 32, lane);
        float m2 = merge_pair(s[2], s[6], 32, lane);
        float m3 = merge_pair(s[3], s[7], 32, lane);
        float n0 = merge_pair(m0, m2, 16, lane);
        float n1 = merge_pair(m1, m3, 16, lane);
        float p  = merge_pair(n0, n1, 8, lane);
        p += __shfl_xor(p, 4, 64);
        p += __shfl_xor(p, 2, 64);
        p += __shfl_xor(p, 1, 64);
        const float r = __shfl(p, (lane & 7) * 8, 64);
        if (lane < U && (k + lane) < k1)
            __builtin_nontemporal_store(r * T_INV, outb + k + lane);
    }
}

__global__ __launch_bounds__(64) void update_kernel(
        const float* __restrict__ x,
        const int*   __restrict__ y,
        const float* __restrict__ memory,
        float*       __restrict__ labels,
        float*       __restrict__ out_mem) {
    const int b    = blockIdx.x;
    const int lane = threadIdx.x;
    const int yb   = y[b];
    const float2 m  = ((const float2*)(memory + (size_t)yb * NDIM))[lane];
    const float2 xv = ((const float2*)(x + (size_t)b * NDIM))[lane];
    float2 v;
    v.x = m.x * MOM + xv.x * (1.0f - MOM);
    v.y = m.y * MOM + xv.y * (1.0f - MOM);
    float s = v.x * v.x + v.y * v.y;
    #pragma unroll
    for (int off = 32; off > 0; off >>= 1)
        s += __shfl_xor(s, off, 64);
    const float n = fmaxf(sqrtf(s), EPS);
    float2 o; o.x = v.x / n; o.y = v.y / n;
    ((float2*)(out_mem + (size_t)yb * NDIM))[lane] = o;
    if (lane == 0) labels[b] = 0.0f;
}

extern "C" void kernel_launch(void* const* d_in, const int* in_sizes, int n_in,
                              void* d_out, int out_size, void* d_ws, size_t ws_size,
                              hipStream_t stream) {
    const float* x      = (const float*)d_in[0];
    const int*   y      = (const int*)  d_in[1];
    const int*   idx    = (const int*)  d_in[2];
    const float* memory = (const float*)d_in[3];

    float* logits  = (float*)d_out;                 // BSZ*KP1
    float* labels  = logits + (size_t)BSZ * KP1;    // BSZ
    float* out_mem = labels + BSZ;                  // NDATA*NDIM

    if (d_ws != nullptr && ws_size >= WS_NEED) {
        float* dots = (float*)d_ws;                 // [16][500000] = 32 MB
        float* xT   = dots + DOTS_ELEMS;            // [128][16]

        xpose_kernel<<<(BSZ * NDIM + 255) / 256, 256, 0, stream>>>(x, xT);
        dots_copy_kernel<<<K1_BLOCKS, 64, 0, stream>>>(memory, xT, dots, out_mem);
        gather_kernel<<<K2_GBLK + BSZ, 256, 0, stream>>>(
            x, y, idx, memory, dots, logits, labels, out_mem);
    } else {
        const int nblocks = NCPY + NBX * BSZ;
        fused_kernel<<<nblocks, 256, 0, stream>>>(
            x, y, idx, memory, logits, (v4f*)out_mem);
        update_kernel<<<BSZ, 64, 0, stream>>>(x, y, memory, labels, out_mem);
    }
}

// Round 6
// 127.276 us; speedup vs baseline: 1.0841x; 1.0841x over previous
//
#include <hip/hip_runtime.h>
#include <math.h>

// Problem constants (from reference setup_inputs)
constexpr int   BSZ   = 16;
constexpr int   NDIM  = 128;
constexpr int   KP1   = 65537;      // K+1
constexpr long  NDATA = 500000;
constexpr float T_INV = 1.0f / 0.07f;
constexpr float MOM   = 0.5f;
constexpr float EPS   = 1e-12f;

typedef float v4f __attribute__((ext_vector_type(4)));

// ---------------- sweep path: sequential sweep + dots table ----------------
constexpr int  TROWS    = 56;                    // rows per tile: 56*129*4B = 28.9KB
                                                 // -> 5 blocks/CU (was 4 at 64 rows)
constexpr int  CHUNKS   = TROWS * (NDIM / 4) / 64;              // 28 v4f per lane
constexpr int  NTILES   = (int)((NDATA + TROWS - 1) / TROWS);   // 8929
constexpr int  LDP      = NDIM + 1;              // 129 pad: column reads 2-way-free
constexpr int  K1_BLOCKS = 1280;                 // 5 single-wave blocks/CU
constexpr int  NLOG     = BSZ * KP1;             // 1,048,592
constexpr long DOTS_ELEMS = (long)BSZ * NDATA;   // 8,000,000 floats (32 MB)
constexpr size_t WS_NEED = (size_t)(DOTS_ELEMS + BSZ * NDIM) * 4;

// k2 XCD-affinity mapping: 257 blocks per batch b, all on XCD b&7
// (bid % 8 == XCD id, learn_hip m09). Each XCD's gather working set =
// 2 dots slices x 2MB = its 4MB L2.
constexpr int  K2_GATHER_BLOCKS = 16 * 257;      // 4112

// k0: transpose x[16][128] -> xT[128][16] (workspace)
__global__ __launch_bounds__(256) void xpose_kernel(
        const float* __restrict__ x, float* __restrict__ xT) {
    const int t = blockIdx.x * 256 + threadIdx.x;
    if (t < BSZ * NDIM) {
        const int b = t >> 7, d = t & 127;
        xT[d * BSZ + b] = x[t];
    }
}

// k1: software-pipelined sequential sweep over memory.
// Per 56-row tile (one wave): regs hold tile t (NT-loaded last iteration);
// drain regs -> LDS (pad-129) + NT copy-store, then ISSUE tile t+stride's
// 28 NT loads (they fly during the dot loop). 28 loads + 28 stores = 56
// outstanding vmem ops per wave -- under the 63-deep vmcnt cap (64-row
// version hit 64 and stalled the last issue). 5 blocks/CU, 1 wave each.
__global__ __launch_bounds__(64, 2) void dots_copy_kernel(
        const float* __restrict__ memory,
        const float* __restrict__ xT,
        float*       __restrict__ dots,
        float*       __restrict__ out) {
    __shared__ float tile[TROWS * LDP];
    const int l = threadIdx.x;
    v4f buf[CHUNKS];

    int t = blockIdx.x;                      // K1_BLOCKS <= NTILES always
    { // prologue: prefetch first tile
        const v4f* __restrict__ srcp = (const v4f*)(memory + (long)t * (TROWS * NDIM));
        const long rem = NDATA - (long)t * TROWS;
        const int nf4 = (int)((rem < TROWS) ? rem : TROWS) * (NDIM / 4);
        #pragma unroll
        for (int c = 0; c < CHUNKS; ++c) {
            int fi = c * 64 + l;
            fi = (fi < nf4) ? fi : (nf4 - 1);
            buf[c] = __builtin_nontemporal_load(srcp + fi);
        }
    }

    while (t < NTILES) {
        const long j0   = (long)t * TROWS;
        const long rem  = NDATA - j0;
        const int  rows = (int)((rem < TROWS) ? rem : TROWS);
        const int  nf4  = rows * (NDIM / 4);
        v4f* __restrict__ dst = (v4f*)(out + j0 * NDIM);

        // A: drain regs -> LDS tile + NT copy-store (reads buf at issue)
        #pragma unroll
        for (int c = 0; c < CHUNKS; ++c) {
            const int fi = c * 64 + l;
            const int r = fi >> 5, col = (fi & 31) * 4;
            float* p = &tile[r * LDP + col];
            p[0] = buf[c].x; p[1] = buf[c].y; p[2] = buf[c].z; p[3] = buf[c].w;
            if (fi < nf4)
                __builtin_nontemporal_store(buf[c], dst + fi);
        }

        // B: issue next tile's loads now; they fly during the compute below
        const int tn = t + K1_BLOCKS;
        if (tn < NTILES) {
            const v4f* __restrict__ srcp =
                (const v4f*)(memory + (long)tn * (TROWS * NDIM));
            const long remn = NDATA - (long)tn * TROWS;
            const int nf4n = (int)((remn < TROWS) ? remn : TROWS) * (NDIM / 4);
            #pragma unroll
            for (int c = 0; c < CHUNKS; ++c) {
                int fi = c * 64 + l;
                fi = (fi < nf4n) ? fi : (nf4n - 1);
                buf[c] = __builtin_nontemporal_load(srcp + fi);
            }
        }

        // C: compute 16 dots for row l from the LDS tile
        float acc[BSZ];
        #pragma unroll
        for (int b = 0; b < BSZ; ++b) acc[b] = 0.0f;

        const int lr = (l < TROWS) ? l : (TROWS - 1);   // lanes 56-63: clamp
        const float* __restrict__ mrow = &tile[lr * LDP];
        #pragma unroll 4
        for (int dd = 0; dd < NDIM; ++dd) {
            const float m = mrow[dd];               // 2-way bank alias: free
            const float* __restrict__ xv = &xT[dd * BSZ];   // wave-uniform
            #pragma unroll
            for (int b = 0; b < BSZ; ++b)
                acc[b] = fmaf(m, xv[b], acc[b]);
        }

        if (l < rows) {
            #pragma unroll
            for (int b = 0; b < BSZ; ++b)
                dots[(long)b * NDATA + j0 + l] = acc[b];   // coalesced 224B
        }
        t = tn;
    }
}

// k2: logits gather (XCD-affine) + fused EMA update.
// Block bid < 4112: XCD k = bid&7 serves batches k and k+8; 257 blocks per
// batch cover 65537 logits. dots slice (2MB/batch) becomes L2-resident on
// its XCD instead of 8x-duplicated L3 traffic. b is derived from bid -- no
// per-thread divide.
__global__ __launch_bounds__(256) void gather_kernel(
        const float* __restrict__ x,
        const int*   __restrict__ y,
        const int*   __restrict__ idx,
        const float* __restrict__ memory,
        const float* __restrict__ dots,
        float*       __restrict__ logits,
        float*       __restrict__ labels,
        float*       __restrict__ out_mem) {
    const int bid = blockIdx.x;
    if (bid < K2_GATHER_BLOCKS) {
        const int k8   = bid & 7;
        const int half = bid >> 3;                   // 0..513
        const int hi   = (half >= 257) ? 1 : 0;
        const int b    = k8 + (hi << 3);             // 0..15, xcd = b&7
        const int s    = half - hi * 257;            // 0..256
        const int off  = s * 256 + threadIdx.x;
        if (off < KP1) {
            const int g = b * KP1 + off;
            const int j = (off == 0) ? y[b] : idx[g];
            logits[g] = dots[(long)b * NDATA + j] * T_INV;
        }
        return;
    }
    // ---- update role: 16 blocks, one wave each ----
    const int b = bid - K2_GATHER_BLOCKS;
    const int lane = threadIdx.x;
    if (lane >= 64) return;
    const int yb = y[b];
    const float2 m  = ((const float2*)(memory + (size_t)yb * NDIM))[lane];
    const float2 xv = ((const float2*)(x + (size_t)b * NDIM))[lane];
    float2 v;
    v.x = m.x * MOM + xv.x * (1.0f - MOM);
    v.y = m.y * MOM + xv.y * (1.0f - MOM);
    float s = v.x * v.x + v.y * v.y;
    #pragma unroll
    for (int off = 32; off > 0; off >>= 1)
        s += __shfl_xor(s, off, 64);
    const float n = fmaxf(sqrtf(s), EPS);
    float2 o; o.x = v.x / n; o.y = v.y / n;
    ((float2*)(out_mem + (size_t)yb * NDIM))[lane] = o;
    if (lane == 0) labels[b] = 0.0f;
}

// ---------------- fallback path (round-3 fused kernel) ----------------
constexpr int U    = 8;
constexpr int NBX  = 128;
constexpr int NCPY = 2048;
constexpr int N4   = (int)(NDATA * NDIM / 4);

__device__ __forceinline__ float merge_pair(float a, float b, int bit, int lane) {
    const float keep = (lane & bit) ? b : a;
    const float send = (lane & bit) ? a : b;
    return keep + __shfl_xor(send, bit, 64);
}

__global__ __launch_bounds__(256, 8) void fused_kernel(
        const float*  __restrict__ x,
        const int*    __restrict__ y,
        const int*    __restrict__ idx,
        const float*  __restrict__ memory,
        float*        __restrict__ logits,
        v4f*          __restrict__ out4) {
    const int bid = blockIdx.x;
    const int sub = bid >> 1;
    if ((bid & 1) == 0) {
        const v4f* __restrict__ src = (const v4f*)memory;
        const int stride = NCPY * 256;
        for (int i = sub * 256 + threadIdx.x; i < N4; i += stride) {
            const v4f v = src[i];
            __builtin_nontemporal_store(v, out4 + i);
        }
        return;
    }
    const int bx   = sub & (NBX - 1);
    const int b    = sub >> 7;
    const int lane = threadIdx.x & 63;
    const int wid  = threadIdx.x >> 6;
    const int nwaves = NBX * 4;
    const int gwave  = bx * 4 + wid;
    const float2 xv = ((const float2*)(x + (size_t)b * NDIM))[lane];
    const int yb = y[b];
    const int* __restrict__ idxb = idx + (size_t)b * KP1;
    const float2* __restrict__ mem2 = (const float2*)memory;
    float* __restrict__ outb = logits + (size_t)b * KP1;
    const int chunk = (KP1 + nwaves - 1) / nwaves;
    const int k0 = gwave * chunk;
    const int k1 = min(k0 + chunk, KP1);
    for (int k = k0; k < k1; k += U) {
        int j[U];
        #pragma unroll
        for (int u = 0; u < U; ++u) {
            int kc = k + u;
            kc = (kc < KP1) ? kc : (KP1 - 1);
            j[u] = (kc == 0) ? yb : idxb[kc];
        }
        float2 m[U];
        #pragma unroll
        for (int u = 0; u < U; ++u)
            m[u] = mem2[(size_t)j[u] * (NDIM / 2) + lane];
        float s[U];
        #pragma unroll
        for (int u = 0; u < U; ++u)
            s[u] = m[u].x * xv.x + m[u].y * xv.y;
        float m0 = merge_pair(s[0], s[4], 32, lane);
        float m1 = merge_pair(s[1], s[5], 32, lane);
        float m2 = merge_pair(s[2], s[6], 32, lane);
        float m3 = merge_pair(s[3], s[7], 32, lane);
        float n0 = merge_pair(m0, m2, 16, lane);
        float n1 = merge_pair(m1, m3, 16, lane);
        float p  = merge_pair(n0, n1, 8, lane);
        p += __shfl_xor(p, 4, 64);
        p += __shfl_xor(p, 2, 64);
        p += __shfl_xor(p, 1, 64);
        const float r = __shfl(p, (lane & 7) * 8, 64);
        if (lane < U && (k + lane) < k1)
            __builtin_nontemporal_store(r * T_INV, outb + k + lane);
    }
}

__global__ __launch_bounds__(64) void update_kernel(
        const float* __restrict__ x,
        const int*   __restrict__ y,
        const float* __restrict__ memory,
        float*       __restrict__ labels,
        float*       __restrict__ out_mem) {
    const int b    = blockIdx.x;
    const int lane = threadIdx.x;
    const int yb   = y[b];
    const float2 m  = ((const float2*)(memory + (size_t)yb * NDIM))[lane];
    const float2 xv = ((const float2*)(x + (size_t)b * NDIM))[lane];
    float2 v;
    v.x = m.x * MOM + xv.x * (1.0f - MOM);
    v.y = m.y * MOM + xv.y * (1.0f - MOM);
    float s = v.x * v.x + v.y * v.y;
    #pragma unroll
    for (int off = 32; off > 0; off >>= 1)
        s += __shfl_xor(s, off, 64);
    const float n = fmaxf(sqrtf(s), EPS);
    float2 o; o.x = v.x / n; o.y = v.y / n;
    ((float2*)(out_mem + (size_t)yb * NDIM))[lane] = o;
    if (lane == 0) labels[b] = 0.0f;
}

extern "C" void kernel_launch(void* const* d_in, const int* in_sizes, int n_in,
                              void* d_out, int out_size, void* d_ws, size_t ws_size,
                              hipStream_t stream) {
    const float* x      = (const float*)d_in[0];
    const int*   y      = (const int*)  d_in[1];
    const int*   idx    = (const int*)  d_in[2];
    const float* memory = (const float*)d_in[3];

    float* logits  = (float*)d_out;                 // BSZ*KP1
    float* labels  = logits + (size_t)BSZ * KP1;    // BSZ
    float* out_mem = labels + BSZ;                  // NDATA*NDIM

    if (d_ws != nullptr && ws_size >= WS_NEED) {
        float* dots = (float*)d_ws;                 // [16][500000] = 32 MB
        float* xT   = dots + DOTS_ELEMS;            // [128][16]

        xpose_kernel<<<(BSZ * NDIM + 255) / 256, 256, 0, stream>>>(x, xT);
        dots_copy_kernel<<<K1_BLOCKS, 64, 0, stream>>>(memory, xT, dots, out_mem);
        gather_kernel<<<K2_GATHER_BLOCKS + BSZ, 256, 0, stream>>>(
            x, y, idx, memory, dots, logits, labels, out_mem);
    } else {
        const int nblocks = NCPY + NBX * BSZ;
        fused_kernel<<<nblocks, 256, 0, stream>>>(
            x, y, idx, memory, logits, (v4f*)out_mem);
        update_kernel<<<BSZ, 64, 0, stream>>>(x, y, memory, labels, out_mem);
    }
}

// Round 8
// 125.361 us; speedup vs baseline: 1.1006x; 1.0153x over previous
//
#include <hip/hip_runtime.h>
#include <math.h>

// Problem constants (from reference setup_inputs)
constexpr int   BSZ   = 16;
constexpr int   NDIM  = 128;
constexpr int   KP1   = 65537;      // K+1
constexpr long  NDATA = 500000;
constexpr float T_INV = 1.0f / 0.07f;
constexpr float MOM   = 0.5f;
constexpr float EPS   = 1e-12f;

typedef float v4f __attribute__((ext_vector_type(4)));

// ---------------- sweep path: sequential sweep + dots table ----------------
constexpr int  TROWS    = 40;                    // 40*129*4B = 20.6KB -> 7 blk/CU
static_assert(NDATA % TROWS == 0, "no tail tiles");
constexpr int  CHUNKS   = TROWS * (NDIM / 4) / 64;              // 20 v4f per lane
constexpr int  NTILES   = (int)(NDATA / TROWS);                 // 12500 exact
constexpr int  LDP      = NDIM + 1;              // 129 pad: column reads 2-way-free
constexpr int  K1_BLOCKS = 1792;                 // 256 CU x 7 blocks
constexpr int  NLOG     = BSZ * KP1;             // 1,048,592
constexpr long DOTS_ELEMS = (long)BSZ * NDATA;   // 8,000,000 floats (32 MB)
constexpr size_t WS_NEED = (size_t)(DOTS_ELEMS + BSZ * NDIM) * 4;

// k2 XCD-affinity mapping: 257 blocks per batch b, all on XCD b&7
// (bid % 8 == XCD id). Each XCD's gather working set = 2 dots slices x 2MB
// = its 4MB L2.
constexpr int  K2_GATHER_BLOCKS = 16 * 257;      // 4112

// k0: transpose x[16][128] -> xT[128][16] (workspace)
__global__ __launch_bounds__(256) void xpose_kernel(
        const float* __restrict__ x, float* __restrict__ xT) {
    const int t = blockIdx.x * 256 + threadIdx.x;
    if (t < BSZ * NDIM) {
        const int b = t >> 7, d = t & 127;
        xT[d * BSZ + b] = x[t];
    }
}

// k1: software-pipelined sequential sweep over memory.
// Per 40-row tile (one wave): regs hold tile t (NT-loaded last iteration);
// drain regs -> LDS (pad-129) + NT copy-store; issue tile t+1792's 20 NT
// loads (they fly during the dot loop); lane l = row l computes 16 fp32
// dots from LDS against xT (wave-uniform dwordx4, L1-hit).
// 20 loads + 20 stores = 40 outstanding vmem < 63 vmcnt cap. Live regs
// ~108 < the 128 cap from (64,2) -> no scratch spill (56-row version held
// 143 and spilled). 7 blocks/CU, 1 wave each, no barriers needed.
__global__ __launch_bounds__(64, 2) void dots_copy_kernel(
        const float* __restrict__ memory,
        const float* __restrict__ xT,
        float*       __restrict__ dots,
        float*       __restrict__ out) {
    __shared__ float tile[TROWS * LDP];
    const int l = threadIdx.x;
    v4f buf[CHUNKS];

    int t = blockIdx.x;                      // K1_BLOCKS <= NTILES always
    { // prologue: prefetch first tile (tiles are always full: 40 | 500000)
        const v4f* __restrict__ srcp =
            (const v4f*)(memory + (long)t * (TROWS * NDIM));
        #pragma unroll
        for (int c = 0; c < CHUNKS; ++c)
            buf[c] = __builtin_nontemporal_load(srcp + c * 64 + l);
    }

    while (t < NTILES) {
        const long j0 = (long)t * TROWS;
        v4f* __restrict__ dst = (v4f*)(out + j0 * NDIM);

        // A: drain regs -> LDS tile + NT copy-store (reads buf at issue)
        #pragma unroll
        for (int c = 0; c < CHUNKS; ++c) {
            const int fi = c * 64 + l;
            const int r = fi >> 5, col = (fi & 31) * 4;
            float* p = &tile[r * LDP + col];
            p[0] = buf[c].x; p[1] = buf[c].y; p[2] = buf[c].z; p[3] = buf[c].w;
            __builtin_nontemporal_store(buf[c], dst + fi);
        }

        // B: issue next tile's loads now; they fly during the compute below
        const int tn = t + K1_BLOCKS;
        if (tn < NTILES) {
            const v4f* __restrict__ srcp =
                (const v4f*)(memory + (long)tn * (TROWS * NDIM));
            #pragma unroll
            for (int c = 0; c < CHUNKS; ++c)
                buf[c] = __builtin_nontemporal_load(srcp + c * 64 + l);
        }

        // C: compute 16 dots for row l from the LDS tile
        float acc[BSZ];
        #pragma unroll
        for (int b = 0; b < BSZ; ++b) acc[b] = 0.0f;

        const int lr = (l < TROWS) ? l : (TROWS - 1);   // lanes 40-63: clamp
        const float* __restrict__ mrow = &tile[lr * LDP];
        #pragma unroll 4
        for (int dd = 0; dd < NDIM; ++dd) {
            const float m = mrow[dd];               // 2-way bank alias: free
            const float* __restrict__ xv = &xT[dd * BSZ];   // wave-uniform
            #pragma unroll
            for (int b = 0; b < BSZ; ++b)
                acc[b] = fmaf(m, xv[b], acc[b]);
        }

        if (l < TROWS) {
            #pragma unroll
            for (int b = 0; b < BSZ; ++b)
                dots[(long)b * NDATA + j0 + l] = acc[b];   // coalesced 160B
        }
        t = tn;
    }
}

// k2: logits gather (XCD-affine) + fused EMA update.
// Block bid < 4112: XCD k = bid&7 serves batches k and k+8; 257 blocks per
// batch cover 65537 logits. dots slice (2MB/batch) stays L2-resident on
// its XCD; idx loads / logits stores are NT so the 8MB stream doesn't
// evict it. b derived from bid -- no per-thread divide.
__global__ __launch_bounds__(256) void gather_kernel(
        const float* __restrict__ x,
        const int*   __restrict__ y,
        const int*   __restrict__ idx,
        const float* __restrict__ memory,
        const float* __restrict__ dots,
        float*       __restrict__ logits,
        float*       __restrict__ labels,
        float*       __restrict__ out_mem) {
    const int bid = blockIdx.x;
    if (bid < K2_GATHER_BLOCKS) {
        const int k8   = bid & 7;
        const int half = bid >> 3;                   // 0..513
        const int hi   = (half >= 257) ? 1 : 0;
        const int b    = k8 + (hi << 3);             // 0..15, xcd = b&7
        const int s    = half - hi * 257;            // 0..256
        const int off  = s * 256 + threadIdx.x;
        if (off < KP1) {
            const int g = b * KP1 + off;
            const int j = (off == 0) ? y[b]
                                     : __builtin_nontemporal_load(idx + g);
            __builtin_nontemporal_store(
                dots[(long)b * NDATA + j] * T_INV, logits + g);
        }
        return;
    }
    // ---- update role: 16 blocks, one wave each ----
    const int b = bid - K2_GATHER_BLOCKS;
    const int lane = threadIdx.x;
    if (lane >= 64) return;
    const int yb = y[b];
    const float2 m  = ((const float2*)(memory + (size_t)yb * NDIM))[lane];
    const float2 xv = ((const float2*)(x + (size_t)b * NDIM))[lane];
    float2 v;
    v.x = m.x * MOM + xv.x * (1.0f - MOM);
    v.y = m.y * MOM + xv.y * (1.0f - MOM);
    float s = v.x * v.x + v.y * v.y;
    #pragma unroll
    for (int off = 32; off > 0; off >>= 1)
        s += __shfl_xor(s, off, 64);
    const float n = fmaxf(sqrtf(s), EPS);
    float2 o; o.x = v.x / n; o.y = v.y / n;
    ((float2*)(out_mem + (size_t)yb * NDIM))[lane] = o;
    if (lane == 0) labels[b] = 0.0f;
}

// ---------------- fallback path (round-3 fused kernel) ----------------
constexpr int U    = 8;
constexpr int NBX  = 128;
constexpr int NCPY = 2048;
constexpr int N4   = (int)(NDATA * NDIM / 4);

__device__ __forceinline__ float merge_pair(float a, float b, int bit, int lane) {
    const float keep = (lane & bit) ? b : a;
    const float send = (lane & bit) ? a : b;
    return keep + __shfl_xor(send, bit, 64);
}

__global__ __launch_bounds__(256, 8) void fused_kernel(
        const float*  __restrict__ x,
        const int*    __restrict__ y,
        const int*    __restrict__ idx,
        const float*  __restrict__ memory,
        float*        __restrict__ logits,
        v4f*          __restrict__ out4) {
    const int bid = blockIdx.x;
    const int sub = bid >> 1;
    if ((bid & 1) == 0) {
        const v4f* __restrict__ src = (const v4f*)memory;
        const int stride = NCPY * 256;
        for (int i = sub * 256 + threadIdx.x; i < N4; i += stride) {
            const v4f v = src[i];
            __builtin_nontemporal_store(v, out4 + i);
        }
        return;
    }
    const int bx   = sub & (NBX - 1);
    const int b    = sub >> 7;
    const int lane = threadIdx.x & 63;
    const int wid  = threadIdx.x >> 6;
    const int nwaves = NBX * 4;
    const int gwave  = bx * 4 + wid;
    const float2 xv = ((const float2*)(x + (size_t)b * NDIM))[lane];
    const int yb = y[b];
    const int* __restrict__ idxb = idx + (size_t)b * KP1;
    const float2* __restrict__ mem2 = (const float2*)memory;
    float* __restrict__ outb = logits + (size_t)b * KP1;
    const int chunk = (KP1 + nwaves - 1) / nwaves;
    const int k0 = gwave * chunk;
    const int k1 = min(k0 + chunk, KP1);
    for (int k = k0; k < k1; k += U) {
        int j[U];
        #pragma unroll
        for (int u = 0; u < U; ++u) {
            int kc = k + u;
            kc = (kc < KP1) ? kc : (KP1 - 1);
            j[u] = (kc == 0) ? yb : idxb[kc];
        }
        float2 m[U];
        #pragma unroll
        for (int u = 0; u < U; ++u)
            m[u] = mem2[(size_t)j[u] * (NDIM / 2) + lane];
        float s[U];
        #pragma unroll
        for (int u = 0; u < U; ++u)
            s[u] = m[u].x * xv.x + m[u].y * xv.y;
        float m0 = merge_pair(s[0], s[4], 32, lane);
        float m1 = merge_pair(s[1], s[5], 32, lane);
        float m2 = merge_pair(s[2], s[6], 32, lane);
        float m3 = merge_pair(s[3], s[7], 32, lane);
        float n0 = merge_pair(m0, m2, 16, lane);
        float n1 = merge_pair(m1, m3, 16, lane);
        float p  = merge_pair(n0, n1, 8, lane);
        p += __shfl_xor(p, 4, 64);
        p += __shfl_xor(p, 2, 64);
        p += __shfl_xor(p, 1, 64);
        const float r = __shfl(p, (lane & 7) * 8, 64);
        if (lane < U && (k + lane) < k1)
            __builtin_nontemporal_store(r * T_INV, outb + k + lane);
    }
}

__global__ __launch_bounds__(64) void update_kernel(
        const float* __restrict__ x,
        const int*   __restrict__ y,
        const float* __restrict__ memory,
        float*       __restrict__ labels,
        float*       __restrict__ out_mem) {
    const int b    = blockIdx.x;
    const int lane = threadIdx.x;
    const int yb   = y[b];
    const float2 m  = ((const float2*)(memory + (size_t)yb * NDIM))[lane];
    const float2 xv = ((const float2*)(x + (size_t)b * NDIM))[lane];
    float2 v;
    v.x = m.x * MOM + xv.x * (1.0f - MOM);
    v.y = m.y * MOM + xv.y * (1.0f - MOM);
    float s = v.x * v.x + v.y * v.y;
    #pragma unroll
    for (int off = 32; off > 0; off >>= 1)
        s += __shfl_xor(s, off, 64);
    const float n = fmaxf(sqrtf(s), EPS);
    float2 o; o.x = v.x / n; o.y = v.y / n;
    ((float2*)(out_mem + (size_t)yb * NDIM))[lane] = o;
    if (lane == 0) labels[b] = 0.0f;
}

extern "C" void kernel_launch(void* const* d_in, const int* in_sizes, int n_in,
                              void* d_out, int out_size, void* d_ws, size_t ws_size,
                              hipStream_t stream) {
    const float* x      = (const float*)d_in[0];
    const int*   y      = (const int*)  d_in[1];
    const int*   idx    = (const int*)  d_in[2];
    const float* memory = (const float*)d_in[3];

    float* logits  = (float*)d_out;                 // BSZ*KP1
    float* labels  = logits + (size_t)BSZ * KP1;    // BSZ
    float* out_mem = labels + BSZ;                  // NDATA*NDIM

    if (d_ws != nullptr && ws_size >= WS_NEED) {
        float* dots = (float*)d_ws;                 // [16][500000] = 32 MB
        float* xT   = dots + DOTS_ELEMS;            // [128][16]

        xpose_kernel<<<(BSZ * NDIM + 255) / 256, 256, 0, stream>>>(x, xT);
        dots_copy_kernel<<<K1_BLOCKS, 64, 0, stream>>>(memory, xT, dots, out_mem);
        gather_kernel<<<K2_GATHER_BLOCKS + BSZ, 256, 0, stream>>>(
            x, y, idx, memory, dots, logits, labels, out_mem);
    } else {
        const int nblocks = NCPY + NBX * BSZ;
        fused_kernel<<<nblocks, 256, 0, stream>>>(
            x, y, idx, memory, logits, (v4f*)out_mem);
        update_kernel<<<BSZ, 64, 0, stream>>>(x, y, memory, labels, out_mem);
    }
}